// Round 8
// baseline (295.411 us; speedup 1.0000x reference)
//
#include <hip/hip_runtime.h>
#include <hip/hip_bf16.h>
#include <hip/hip_cooperative_groups.h>

namespace cg = cooperative_groups;

// SimilarityPreserving loss, O(b*d^2) factorization (b=8192, d=128):
//   loss = (1/b^2) * sum_i 2*(1 - rho_i),  rho_i = C_i / sqrt(A_i*B_i)
//   A_i = xt_i^T Gt xt_i,  Gt = Yt_hat^T Yt_hat  (Yt_hat = row-normalized zyt)
//   B_i = xs_i^T Gs xs_i,  Gs = Ys_hat^T Ys_hat
//   C_i = xt_i^T M  xs_i,  M  = Yt_hat^T Ys_hat
// X normalization and temperature fold out of rho (scale invariance); eps
// never binds. Math verified R5-R7 (absmax 0.0).
//
// R8: single cooperative kernel (256 blocks x 256 thr = 1 block/CU), 4 phases
// separated by grid.sync() — replaces 4 dispatches + 3 graph-node gaps.
// R7 analysis: our kernels total ~12-15 us vs ~95 us harness floor (ws fill
// 41 us + restores + node overheads); dispatch count is the remaining lever.
// Partials stored bf16 (slab 6.3 MB): G-entry error ~5e-4 rel, loss tol 2%.

typedef __attribute__((ext_vector_type(8))) short short8;   // 8 bf16
typedef __attribute__((ext_vector_type(4))) float float4v;  // MFMA C/D

#define BSZ 8192
#define DIM 128
#define NP  64           // k-splits per gram (K=128 each)
#define INV_B2 1.4901161193847656e-08f  // 1/8192^2

__device__ __forceinline__ short f2bf(float x) {
    union { __hip_bfloat16 b; short s; } u;
    u.b = __float2bfloat16(x);
    return u.s;
}
__device__ __forceinline__ float bf2f(short s) {
    union { unsigned int u; float f; } v;
    v.u = ((unsigned int)(unsigned short)s) << 16;
    return v.f;
}

__global__ void __launch_bounds__(256, 1) fused(
    const float* __restrict__ Yt, const float* __restrict__ Ys,
    const float* __restrict__ Xt, const float* __restrict__ Xs,
    short* __restrict__ YT,        // [mat][d][8192] bf16, 4 MB
    short* __restrict__ partial,   // [gram][split][d1][d2] bf16, 6.3 MB
    short* __restrict__ Gb,        // [gram][d2][d1] bf16, 96 KB
    float* __restrict__ out)
{
    cg::grid_group grid = cg::this_grid();

    const int tid  = threadIdx.x;
    const int lane = tid & 63;
    const int wave = tid >> 6;     // 0..3
    const int q    = lane >> 4;
    const int l15  = lane & 15;
    const int bid  = blockIdx.x;   // 0..255

    // ================= phase A: normalize Y, write transposed bf16 =========
    // block -> (chunk = bid&127, mat = bid>>7); thread owns column d for 32 rows.
    {
        __shared__ float rsum[2][64];
        __shared__ float invn[64];
        const int d     = tid & 127;
        const int khalf = tid >> 7;
        const int chunk = bid & 127;
        const int mat   = bid >> 7;
        const float* Y  = mat ? Ys : Yt;

        if (bid == 0 && tid == 0) out[0] = 0.f;

        float v[32];
        const float* base = Y + (size_t)(chunk * 64 + khalf * 32) * DIM + d;
        #pragma unroll
        for (int i = 0; i < 32; ++i) v[i] = base[(size_t)i * DIM];

        #pragma unroll
        for (int i = 0; i < 32; ++i) {
            float ss = v[i] * v[i];
            #pragma unroll
            for (int off = 1; off < 64; off <<= 1) ss += __shfl_xor(ss, off);
            if (lane == 0) rsum[wave & 1][khalf * 32 + i] = ss;
        }
        __syncthreads();
        if (tid < 64) {
            float s = rsum[0][tid] + rsum[1][tid];
            invn[tid] = (s > 0.f) ? rsqrtf(s) : 0.f;
        }
        __syncthreads();

        short* yt = YT + ((size_t)mat * 128 + d) * BSZ + chunk * 64 + khalf * 32;
        #pragma unroll
        for (int g = 0; g < 4; ++g) {
            short8 pk;
            #pragma unroll
            for (int j = 0; j < 8; ++j) {
                int i = g * 8 + j;
                pk[j] = f2bf(v[i] * invn[khalf * 32 + i]);
            }
            *(short8*)&yt[g * 8] = pk;
        }
    }
    __threadfence();
    grid.sync();

    // ================= phase B: partial grams (bf16), no LDS ===============
    // 384 units: (split 0..63, gram 0..2, half 0..1); wave = d1-strip within half.
    for (int u = bid; u < 384; u += 256) {
        const int split = u & 63;
        const int rest  = u >> 6;       // 0..5
        const int gram  = rest >> 1;    // 0=Gt 1=Gs 2=M
        const int half  = rest & 1;
        const int s1    = half * 4 + wave;

        const short* Ta = (gram == 1) ? YT + (size_t)128 * BSZ : YT;
        const short* Tb = (gram == 0) ? YT : YT + (size_t)128 * BSZ;
        const int k0 = split * 128;

        float4v acc[8];
        #pragma unroll
        for (int s2 = 0; s2 < 8; ++s2) acc[s2] = (float4v){0.f, 0.f, 0.f, 0.f};

        #pragma unroll
        for (int kk = 0; kk < 4; ++kk) {
            const int ko = k0 + kk * 32 + q * 8;
            short8 fa = *(const short8*)&Ta[(size_t)(s1 * 16 + l15) * BSZ + ko];
            short8 fb[8];
            #pragma unroll
            for (int s2 = 0; s2 < 8; ++s2)
                fb[s2] = *(const short8*)&Tb[(size_t)(s2 * 16 + l15) * BSZ + ko];
            #pragma unroll
            for (int s2 = 0; s2 < 8; ++s2)
                acc[s2] = __builtin_amdgcn_mfma_f32_16x16x32_bf16(fa, fb[s2], acc[s2], 0, 0, 0);
        }

        // D tile: d1 = s1*16 + q*4 + r, d2 = s2*16 + l15
        short* P = partial + ((size_t)(gram * NP + split) << 14);
        #pragma unroll
        for (int s2 = 0; s2 < 8; ++s2)
            #pragma unroll
            for (int r = 0; r < 4; ++r)
                P[((s1 * 16 + q * 4 + r) << 7) + s2 * 16 + l15] = f2bf(acc[s2][r]);
    }
    __threadfence();
    grid.sync();

    // ================= phase C: reduce partials -> Gb (transposed) =========
    {
        int o = bid * 256 + tid;     // 0..65535; need < 3*16384
        if (o < 3 * 16384) {
            int g = o >> 14, rem = o & 16383;
            const short* P = partial + ((size_t)(g * NP) << 14) + rem;
            float s = 0.f;
            #pragma unroll 8
            for (int b = 0; b < NP; ++b) s += bf2f(P[(size_t)b << 14]);
            int d1 = rem >> 7, d2 = rem & 127;
            Gb[(g << 14) + (d2 << 7) + d1] = f2bf(s);
        }
    }
    __threadfence();
    grid.sync();

    // ================= phase D: quadratic forms + loss =====================
    if (bid < 128) {
        const int rbase = bid * 64 + wave * 16;

        // A-frags: lane holds X[rbase+l15][kk*32+q*8 ..+8) as bf16
        short8 At[4], As[4];
        #pragma unroll
        for (int kk = 0; kk < 4; ++kk) {
            const float* pt = Xt + (size_t)(rbase + l15) * DIM + kk * 32 + q * 8;
            const float* ps = Xs + (size_t)(rbase + l15) * DIM + kk * 32 + q * 8;
            float4 t0 = *(const float4*)pt, t1 = *(const float4*)(pt + 4);
            float4 s0 = *(const float4*)ps, s1 = *(const float4*)(ps + 4);
            short8 a, b;
            a[0]=f2bf(t0.x); a[1]=f2bf(t0.y); a[2]=f2bf(t0.z); a[3]=f2bf(t0.w);
            a[4]=f2bf(t1.x); a[5]=f2bf(t1.y); a[6]=f2bf(t1.z); a[7]=f2bf(t1.w);
            b[0]=f2bf(s0.x); b[1]=f2bf(s0.y); b[2]=f2bf(s0.z); b[3]=f2bf(s0.w);
            b[4]=f2bf(s1.x); b[5]=f2bf(s1.y); b[6]=f2bf(s1.z); b[7]=f2bf(s1.w);
            At[kk] = a; As[kk] = b;
        }

        float fA[4] = {0,0,0,0}, fB[4] = {0,0,0,0}, fC[4] = {0,0,0,0};

        #pragma unroll
        for (int nt = 0; nt < 8; ++nt) {
            int d2 = nt * 16 + l15;
            float4v qt = {0.f,0.f,0.f,0.f}, qs = qt, qc = qt;
            #pragma unroll
            for (int kk = 0; kk < 4; ++kk) {
                int off = (d2 << 7) + kk * 32 + q * 8;
                short8 Bt = *(const short8*)&Gb[off];
                short8 Bs = *(const short8*)&Gb[16384 + off];
                short8 Bm = *(const short8*)&Gb[32768 + off];
                qt = __builtin_amdgcn_mfma_f32_16x16x32_bf16(At[kk], Bt, qt, 0, 0, 0);
                qs = __builtin_amdgcn_mfma_f32_16x16x32_bf16(As[kk], Bs, qs, 0, 0, 0);
                qc = __builtin_amdgcn_mfma_f32_16x16x32_bf16(At[kk], Bm, qc, 0, 0, 0);
            }
            #pragma unroll
            for (int r = 0; r < 4; ++r) {
                int row = rbase + q * 4 + r;
                float xtv = Xt[(size_t)row * DIM + d2];
                float xsv = Xs[(size_t)row * DIM + d2];
                fA[r] += qt[r] * xtv;
                fB[r] += qs[r] * xsv;
                fC[r] += qc[r] * xsv;
            }
        }

        float wl = 0.f;
        #pragma unroll
        for (int r = 0; r < 4; ++r) {
            float A = fA[r], B = fB[r], C = fC[r];
            #pragma unroll
            for (int off = 1; off < 16; off <<= 1) {
                A += __shfl_xor(A, off);
                B += __shfl_xor(B, off);
                C += __shfl_xor(C, off);
            }
            float contrib = 2.f - 2.f * C * rsqrtf(A * B);
            wl += (l15 == 0) ? contrib : 0.f;
        }
        wl += __shfl_xor(wl, 16);
        wl += __shfl_xor(wl, 32);

        __shared__ float wred[4];
        if (lane == 0) wred[wave] = wl;
        __syncthreads();
        if (tid == 0)
            atomicAdd(out, (wred[0] + wred[1] + wred[2] + wred[3]) * INV_B2);
    }
}

// ---------------------------------------------------------------- launch
extern "C" void kernel_launch(void* const* d_in, const int* in_sizes, int n_in,
                              void* d_out, int out_size, void* d_ws, size_t ws_size,
                              hipStream_t stream) {
    const float* zxs = (const float*)d_in[0];
    const float* zys = (const float*)d_in[1];
    const float* zxt = (const float*)d_in[2];
    const float* zyt = (const float*)d_in[3];
    // d_in[4] = temperature: folds out of rho, unused.
    float* out = (float*)d_out;

    char* ws = (char*)d_ws;
    short* YT      = (short*)ws;                               // 4 MB
    short* partial = (short*)(ws + (size_t)4  * 1024 * 1024);  // 6.3 MB
    short* Gb      = (short*)(ws + (size_t)11 * 1024 * 1024);  // 96 KB

    void* args[] = {(void*)&zyt, (void*)&zys, (void*)&zxt, (void*)&zxs,
                    (void*)&YT, (void*)&partial, (void*)&Gb, (void*)&out};
    hipLaunchCooperativeKernel((const void*)fused, dim3(256), dim3(256),
                               args, 0, stream);
}

// Round 9
// 109.712 us; speedup vs baseline: 2.6926x; 2.6926x over previous
//
#include <hip/hip_runtime.h>
#include <hip/hip_bf16.h>

// SimilarityPreserving loss, O(b*d^2) factorization (b=8192, d=128):
//   loss = (1/b^2) * sum_i 2*(1 - rho_i),  rho_i = C_i / sqrt(A_i*B_i)
//   A_i = xt_i^T Gt xt_i,  Gt = Yt_hat^T Yt_hat  (Yt_hat = row-normalized zyt)
//   B_i = xs_i^T Gs xs_i,  Gs = Ys_hat^T Ys_hat
//   C_i = xt_i^T M  xs_i,  M  = Yt_hat^T Ys_hat
// X normalization and temperature fold out of rho (scale invariance); eps
// never binds. Math verified R5-R8 (absmax 0.0).
//
// R9 = R7 (best: 109.09 us) + bf16 partial slab (validated accurate in R8).
// R8 post-mortem: cooperative grid.sync() costs ~60-70 us per sync on this
// harness — never fuse sub-100us phases with grid sync; graph-node
// boundaries are far cheaper. Reverted to the 4-dispatch pipeline.

typedef __attribute__((ext_vector_type(8))) short short8;   // 8 bf16
typedef __attribute__((ext_vector_type(4))) float float4v;  // MFMA C/D

#define BSZ 8192
#define DIM 128
#define NP  64           // k-splits per gram (K=128 each)
#define INV_B2 1.4901161193847656e-08f  // 1/8192^2

__device__ __forceinline__ short f2bf(float x) {
    union { __hip_bfloat16 b; short s; } u;
    u.b = __float2bfloat16(x);
    return u.s;
}
__device__ __forceinline__ float bf2f(short s) {
    union { unsigned int u; float f; } v;
    v.u = ((unsigned int)(unsigned short)s) << 16;
    return v.f;
}

// ---------------------------------------------------------------- stage 0
// prep: block (chunk, mat) normalizes 64 rows of one Y and writes them
// TRANSPOSED bf16 into YT[mat][d][8192]. Thread owns column d for 32 rows:
// loads coalesced, transposed stores per-thread contiguous 64 B. Norms once.
__global__ __launch_bounds__(256) void prep(
    const float* __restrict__ Yt, const float* __restrict__ Ys,
    short* __restrict__ YT, float* __restrict__ out)
{
    __shared__ float rsum[2][64];
    __shared__ float invn[64];

    const int tid   = threadIdx.x;
    const int lane  = tid & 63;
    const int wave  = tid >> 6;     // 0..3; wave&1 = d-half
    const int d     = tid & 127;
    const int khalf = tid >> 7;     // 0/1: row half
    const int chunk = blockIdx.x;   // 0..127
    const int mat   = blockIdx.y;   // 0..1
    const float* Y  = mat ? Ys : Yt;

    if (chunk == 0 && mat == 0 && tid == 0) out[0] = 0.f;

    float v[32];
    const float* base = Y + (size_t)(chunk * 64 + khalf * 32) * DIM + d;
    #pragma unroll
    for (int i = 0; i < 32; ++i) v[i] = base[(size_t)i * DIM];

    #pragma unroll
    for (int i = 0; i < 32; ++i) {
        float ss = v[i] * v[i];
        #pragma unroll
        for (int off = 1; off < 64; off <<= 1) ss += __shfl_xor(ss, off);
        if (lane == 0) rsum[wave & 1][khalf * 32 + i] = ss;
    }
    __syncthreads();
    if (tid < 64) {
        float s = rsum[0][tid] + rsum[1][tid];
        invn[tid] = (s > 0.f) ? rsqrtf(s) : 0.f;
    }
    __syncthreads();

    short* yt = YT + ((size_t)mat * 128 + d) * BSZ + chunk * 64 + khalf * 32;
    #pragma unroll
    for (int g = 0; g < 4; ++g) {
        short8 pk;
        #pragma unroll
        for (int j = 0; j < 8; ++j) {
            int i = g * 8 + j;
            pk[j] = f2bf(v[i] * invn[khalf * 32 + i]);
        }
        *(short8*)&yt[g * 8] = pk;
    }
}

// ---------------------------------------------------------------- stage 1
// Block (split, gram): bf16 partial G over k-rows [split*128, +128).
// 8 waves, wave = d1-strip. Fragments load straight from YT (contiguous 16B
// per lane). 32 MFMA/wave, no LDS, no barriers.
__global__ __launch_bounds__(512) void gram_g(
    const short* __restrict__ YT, short* __restrict__ partial)
{
    const int tid  = threadIdx.x;
    const int lane = tid & 63;
    const int s1   = tid >> 6;    // wave = d1 strip 0..7
    const int q    = lane >> 4;
    const int l15  = lane & 15;
    const int split = blockIdx.x; // 0..NP-1
    const int gram  = blockIdx.y; // 0=Gt 1=Gs 2=M

    const short* Ta = (gram == 1) ? YT + (size_t)128 * BSZ : YT;  // Gs->Ys
    const short* Tb = (gram == 0) ? YT : YT + (size_t)128 * BSZ;  // Gt->Yt
    const int k0 = split * 128;

    float4v acc[8];
    #pragma unroll
    for (int s2 = 0; s2 < 8; ++s2) acc[s2] = (float4v){0.f, 0.f, 0.f, 0.f};

    #pragma unroll
    for (int kk = 0; kk < 4; ++kk) {
        const int ko = k0 + kk * 32 + q * 8;
        short8 fa = *(const short8*)&Ta[(size_t)(s1 * 16 + l15) * BSZ + ko];
        short8 fb[8];
        #pragma unroll
        for (int s2 = 0; s2 < 8; ++s2)
            fb[s2] = *(const short8*)&Tb[(size_t)(s2 * 16 + l15) * BSZ + ko];
        #pragma unroll
        for (int s2 = 0; s2 < 8; ++s2)
            acc[s2] = __builtin_amdgcn_mfma_f32_16x16x32_bf16(fa, fb[s2], acc[s2], 0, 0, 0);
    }

    // D tile: d1 = s1*16 + q*4 + r, d2 = s2*16 + l15.
    short* P = partial + ((size_t)(gram * NP + split) << 14);
    #pragma unroll
    for (int s2 = 0; s2 < 8; ++s2)
        #pragma unroll
        for (int r = 0; r < 4; ++r)
            P[((s1 * 16 + q * 4 + r) << 7) + s2 * 16 + l15] = f2bf(acc[s2][r]);
}

// ---------------------------------------------------------------- stage 2
// Sum NP bf16 partials -> Gb[g][d2][d1] bf16 (transposed so quad_k's
// B-fragments are contiguous 16B loads).
__global__ __launch_bounds__(512) void reduce_g(
    const short* __restrict__ partial, short* __restrict__ Gb)
{
    int o = blockIdx.x * 512 + threadIdx.x;   // < 3*16384
    int g = o >> 14, rem = o & 16383;
    const short* P = partial + ((size_t)(g * NP) << 14) + rem;
    float s = 0.f;
    #pragma unroll 8
    for (int b = 0; b < NP; ++b) s += bf2f(P[(size_t)b << 14]);
    int d1 = rem >> 7, d2 = rem & 127;
    Gb[(g << 14) + (d2 << 7) + d1] = f2bf(s);
}

// ---------------------------------------------------------------- stage 3
// Per row i: Q = x^T G via MFMA, fold Q.x -> A,B,C; rho; atomicAdd loss.
// Raw fp32 X (normalization folds out of rho). 128 blocks x 4 waves x 16 rows.
__global__ __launch_bounds__(256) void quad_k(
    const float* __restrict__ Xt, const float* __restrict__ Xs,
    const short* __restrict__ Gb, float* __restrict__ out)
{
    const int tid  = threadIdx.x;
    const int lane = tid & 63;
    const int wave = tid >> 6;
    const int q    = lane >> 4;
    const int l15  = lane & 15;
    const int rbase = blockIdx.x * 64 + wave * 16;

    // A-frags: lane holds X[rbase+l15][kk*32+q*8 ..+8) as bf16
    short8 At[4], As[4];
    #pragma unroll
    for (int kk = 0; kk < 4; ++kk) {
        const float* pt = Xt + (size_t)(rbase + l15) * DIM + kk * 32 + q * 8;
        const float* ps = Xs + (size_t)(rbase + l15) * DIM + kk * 32 + q * 8;
        float4 t0 = *(const float4*)pt, t1 = *(const float4*)(pt + 4);
        float4 s0 = *(const float4*)ps, s1 = *(const float4*)(ps + 4);
        short8 a, b;
        a[0]=f2bf(t0.x); a[1]=f2bf(t0.y); a[2]=f2bf(t0.z); a[3]=f2bf(t0.w);
        a[4]=f2bf(t1.x); a[5]=f2bf(t1.y); a[6]=f2bf(t1.z); a[7]=f2bf(t1.w);
        b[0]=f2bf(s0.x); b[1]=f2bf(s0.y); b[2]=f2bf(s0.z); b[3]=f2bf(s0.w);
        b[4]=f2bf(s1.x); b[5]=f2bf(s1.y); b[6]=f2bf(s1.z); b[7]=f2bf(s1.w);
        At[kk] = a; As[kk] = b;
    }

    float fA[4] = {0,0,0,0}, fB[4] = {0,0,0,0}, fC[4] = {0,0,0,0};

    #pragma unroll
    for (int nt = 0; nt < 8; ++nt) {
        int d2 = nt * 16 + l15;
        float4v qt = {0.f,0.f,0.f,0.f}, qs = qt, qc = qt;
        #pragma unroll
        for (int kk = 0; kk < 4; ++kk) {
            int off = (d2 << 7) + kk * 32 + q * 8;
            short8 Bt = *(const short8*)&Gb[off];
            short8 Bs = *(const short8*)&Gb[16384 + off];
            short8 Bm = *(const short8*)&Gb[32768 + off];
            qt = __builtin_amdgcn_mfma_f32_16x16x32_bf16(At[kk], Bt, qt, 0, 0, 0);
            qs = __builtin_amdgcn_mfma_f32_16x16x32_bf16(As[kk], Bs, qs, 0, 0, 0);
            qc = __builtin_amdgcn_mfma_f32_16x16x32_bf16(At[kk], Bm, qc, 0, 0, 0);
        }
        // fold: D row = q*4+r, col = l15 -> Q[row][d2]; A += Q*x, etc.
        #pragma unroll
        for (int r = 0; r < 4; ++r) {
            int row = rbase + q * 4 + r;
            float xtv = Xt[(size_t)row * DIM + d2];
            float xsv = Xs[(size_t)row * DIM + d2];
            fA[r] += qt[r] * xtv;
            fB[r] += qs[r] * xsv;
            fC[r] += qc[r] * xsv;
        }
    }

    float wl = 0.f;
    #pragma unroll
    for (int r = 0; r < 4; ++r) {
        float A = fA[r], B = fB[r], C = fC[r];
        #pragma unroll
        for (int off = 1; off < 16; off <<= 1) {
            A += __shfl_xor(A, off);
            B += __shfl_xor(B, off);
            C += __shfl_xor(C, off);
        }
        float contrib = 2.f - 2.f * C * rsqrtf(A * B);
        wl += (l15 == 0) ? contrib : 0.f;
    }
    wl += __shfl_xor(wl, 16);
    wl += __shfl_xor(wl, 32);

    __shared__ float wred[4];
    if (lane == 0) wred[wave] = wl;
    __syncthreads();
    if (tid == 0)
        atomicAdd(out, (wred[0] + wred[1] + wred[2] + wred[3]) * INV_B2);
}

// ---------------------------------------------------------------- launch
extern "C" void kernel_launch(void* const* d_in, const int* in_sizes, int n_in,
                              void* d_out, int out_size, void* d_ws, size_t ws_size,
                              hipStream_t stream) {
    const float* zxs = (const float*)d_in[0];
    const float* zys = (const float*)d_in[1];
    const float* zxt = (const float*)d_in[2];
    const float* zyt = (const float*)d_in[3];
    // d_in[4] = temperature: folds out of rho, unused.
    float* out = (float*)d_out;

    char* ws = (char*)d_ws;
    short* YT      = (short*)ws;                               // 4 MB
    short* partial = (short*)(ws + (size_t)4  * 1024 * 1024);  // 6.3 MB bf16
    short* Gb      = (short*)(ws + (size_t)11 * 1024 * 1024);  // 96 KB

    prep    <<<dim3(128, 2), 256, 0, stream>>>(zyt, zys, YT, out);
    gram_g  <<<dim3(NP, 3),  512, 0, stream>>>(YT, partial);
    reduce_g<<<96,           512, 0, stream>>>(partial, Gb);
    quad_k  <<<128,          256, 0, stream>>>(zxt, zxs, Gb, out);
}